// Round 1
// baseline (97173.456 us; speedup 1.0000x reference)
//
#include <hip/hip_runtime.h>
#include <math.h>

#define BATCH 128
#define TSTEPS 1024
#define INSZ 256
#define HSZ 256
#define MEMN 128

#define NWG_A 128
#define NWG_B 64
#define NWG_C 32
#define NWG 224
#define NTHR 256

#define GATE_C 0.40131233988754794f
#define OMG_C (1.0f - GATE_C)
#define GAMMA_C 0.3f

// ---------------- persistent state (re-initialized every launch) ----------------
__device__ float g_h[2][BATCH * HSZ];    // hidden, double-buffered by step parity
__device__ float g_c[BATCH * HSZ];       // cell state, owner-updated in place
__device__ float g_M[2][MEMN * HSZ];     // memory rows, double-buffered
__device__ float g_MT[2][HSZ * MEMN];    // memory transposed, double-buffered
__device__ float g_wu[BATCH * MEMN];     // usage weights, owner-updated in place
__device__ float g_ww[2][BATCH * MEMN];  // write weights, double-buffered
__device__ float g_Mn[2][MEMN];          // per-row memory norms, double-buffered
__device__ int g_ctrl[2];                // {arrive, release} for grid barrier

__global__ void reset_ctrl_kernel() {
    g_ctrl[0] = 0;
    g_ctrl[1] = 0;
}

__device__ __forceinline__ float sigf(float x) { return 1.0f / (1.0f + expf(-x)); }

// monotonic-counter grid barrier (224 WGs, all co-resident)
__device__ __forceinline__ void gridbar(int seq) {
    __syncthreads();
    if (threadIdx.x == 0) {
        __threadfence();
        int v = __hip_atomic_fetch_add(&g_ctrl[0], 1, __ATOMIC_ACQ_REL, __HIP_MEMORY_SCOPE_AGENT);
        if (v == NWG * seq - 1) {
            __hip_atomic_store(&g_ctrl[1], seq, __ATOMIC_RELEASE, __HIP_MEMORY_SCOPE_AGENT);
        } else {
            while (__hip_atomic_load(&g_ctrl[1], __ATOMIC_ACQUIRE, __HIP_MEMORY_SCOPE_AGENT) < seq) {
                __builtin_amdgcn_s_sleep(8);
            }
        }
        __threadfence();
    }
    __syncthreads();
}

__global__ void __launch_bounds__(NTHR, 1)
mann_persist(const float* __restrict__ X, const float* __restrict__ Wih,
             const float* __restrict__ Whh, const float* __restrict__ bih,
             const float* __restrict__ bhh, float* __restrict__ out) {
    __shared__ float s_xh[2 * (INSZ + HSZ)];  // A: [2 batches][512]
    __shared__ float s_h[HSZ];                // B
    __shared__ float s_in[2 * MEMN];          // B: inner-product halves
    __shared__ float s_wr[MEMN];              // B
    __shared__ float s_wwc[BATCH];            // C
    __shared__ float s_red[4];
    __shared__ unsigned long long s_redu[4];

    const int w = blockIdx.x;
    const int tid = threadIdx.x;

    // ---- block reductions (all 256 threads must call) ----
    auto brsum = [&](float v) -> float {
#pragma unroll
        for (int o = 32; o; o >>= 1) v += __shfl_xor(v, o, 64);
        if ((tid & 63) == 0) s_red[tid >> 6] = v;
        __syncthreads();
        v = (s_red[0] + s_red[1]) + (s_red[2] + s_red[3]);
        __syncthreads();
        return v;
    };
    auto brmax = [&](float v) -> float {
#pragma unroll
        for (int o = 32; o; o >>= 1) v = fmaxf(v, __shfl_xor(v, o, 64));
        if ((tid & 63) == 0) s_red[tid >> 6] = v;
        __syncthreads();
        v = fmaxf(fmaxf(s_red[0], s_red[1]), fmaxf(s_red[2], s_red[3]));
        __syncthreads();
        return v;
    };
    auto brminu = [&](unsigned long long v) -> unsigned long long {
#pragma unroll
        for (int o = 32; o; o >>= 1) {
            unsigned long long o2 = __shfl_xor(v, o, 64);
            v = (o2 < v) ? o2 : v;
        }
        if ((tid & 63) == 0) s_redu[tid >> 6] = v;
        __syncthreads();
        unsigned long long a = (s_redu[0] < s_redu[1]) ? s_redu[0] : s_redu[1];
        unsigned long long b = (s_redu[2] < s_redu[3]) ? s_redu[2] : s_redu[3];
        v = (a < b) ? a : b;
        __syncthreads();
        return v;
    };

    // ---- init all state (deterministic per launch) ----
    {
        const int gt = w * NTHR + tid, gn = NWG * NTHR;
        for (int i = gt; i < BATCH * HSZ; i += gn) { g_h[1][i] = 0.f; g_c[i] = 0.f; }
        for (int i = gt; i < MEMN * HSZ; i += gn) { g_M[0][i] = 0.f; g_MT[0][i] = 0.f; }
        for (int i = gt; i < BATCH * MEMN; i += gn) {
            g_wu[i] = 0.f;
            g_ww[0][i] = ((i & (MEMN - 1)) == 0) ? OMG_C : 0.f;  // t=0: argmin(zeros)=0
        }
        for (int i = gt; i < MEMN; i += gn) g_Mn[0][i] = 0.f;
    }

    // ---- per-thread role constants ----
    const int bpair = w >> 1;        // A: batch pair
    const int jh = w & 1;            // A: j half
    const int b01 = tid >> 7;        // A: which batch of pair
    const int jA = jh * 128 + (tid & 127);
    float biasA[4] = {0.f, 0.f, 0.f, 0.f};
    if (w < NWG_A) {
#pragma unroll
        for (int g = 0; g < 4; ++g) {
            const int row = g * HSZ + jA;
            biasA[g] = bih[row] + bhh[row];
        }
    }

    // ---- phase A: LSTM cell for step t (reads hprev, writes hout + g_c) ----
    auto phaseA = [&](int t, const float* hprev, float* hout) {
        const int bA = bpair * 2;
        for (int i = tid; i < 2 * (INSZ + HSZ); i += NTHR) {
            const int bs = i >> 9, k = i & 511;
            s_xh[i] = (k < INSZ) ? X[((size_t)(bA + bs) * TSTEPS + t) * INSZ + k]
                                 : hprev[(bA + bs) * HSZ + (k - INSZ)];
        }
        __syncthreads();
        const float4* xh4 = (const float4*)(s_xh + b01 * 512);
        float z[4];
#pragma unroll
        for (int g = 0; g < 4; ++g) {
            const int row = g * HSZ + jA;
            const float4* wa = (const float4*)(Wih + (size_t)row * INSZ);
            const float4* wb = (const float4*)(Whh + (size_t)row * HSZ);
            float4 a1 = make_float4(0.f, 0.f, 0.f, 0.f);
            float4 a2 = make_float4(0.f, 0.f, 0.f, 0.f);
#pragma unroll 8
            for (int c = 0; c < 64; ++c) {
                float4 wv = wa[c], xv = xh4[c];
                a1.x += wv.x * xv.x; a1.y += wv.y * xv.y;
                a1.z += wv.z * xv.z; a1.w += wv.w * xv.w;
            }
#pragma unroll 8
            for (int c = 0; c < 64; ++c) {
                float4 wv = wb[c], xv = xh4[64 + c];
                a2.x += wv.x * xv.x; a2.y += wv.y * xv.y;
                a2.z += wv.z * xv.z; a2.w += wv.w * xv.w;
            }
            z[g] = ((a1.x + a1.y) + (a1.z + a1.w)) + ((a2.x + a2.y) + (a2.z + a2.w)) + biasA[g];
        }
        const int idx = (bA + b01) * HSZ + jA;
        const float cold = g_c[idx];
        const float cn = sigf(z[1]) * cold + sigf(z[0]) * tanhf(z[2]);
        const float hn = sigf(z[3]) * tanhf(cn);
        g_c[idx] = cn;
        hout[idx] = hn;
    };

    // ---- phase B: read head + output + w_u/w_w update for step t ----
    auto phaseB = [&](int t, const float* hcur, const float* Mcur, const float* MTcur,
                      const float* Mncur, const float* wwcur, float* wwnxt) {
        const int bwg = w - NWG_A;
        for (int bi = 0; bi < 2; ++bi) {
            const int b = bwg * 2 + bi;
            const float hv = hcur[b * HSZ + tid];
            s_h[tid] = hv;
            __syncthreads();
            const float hnorm = sqrtf(brsum(hv * hv));
            {  // inner = h . M[m] split into two j-halves
                const int m = tid & (MEMN - 1);
                const int hf = tid >> 7;
                const float* mt = MTcur + hf * 128 * MEMN;
                const float* hh = s_h + hf * 128;
                float acc = 0.f;
#pragma unroll 8
                for (int j = 0; j < 128; ++j) acc += mt[j * MEMN + m] * hh[j];
                s_in[tid] = acc;
            }
            __syncthreads();
            float sc = -1e30f;
            if (tid < MEMN) {
                const float inner = s_in[tid] + s_in[MEMN + tid];
                sc = inner / (hnorm * Mncur[tid] + 1e-8f);
            }
            const float mx = brmax(sc);
            const float ev = (tid < MEMN) ? expf(sc - mx) : 0.f;
            const float es = brsum(ev);
            const float wr = ev / es;
            if (tid < MEMN) s_wr[tid] = wr;
            __syncthreads();
            float rd = 0.f;
#pragma unroll 8
            for (int m2 = 0; m2 < MEMN; ++m2) rd += s_wr[m2] * Mcur[m2 * HSZ + tid];
            float* op = out + ((size_t)b * TSTEPS + t) * (2 * HSZ);
            op[tid] = hv;
            op[HSZ + tid] = rd;
            // w_u(t+1) = l2norm(gamma*w_u + w_r + w_w); then w_w(t+1) from argmin
            float un = 0.f;
            if (tid < MEMN) un = GAMMA_C * g_wu[b * MEMN + tid] + wr + wwcur[b * MEMN + tid];
            const float un2 = brsum(un * un);
            const float us = 1.0f / fmaxf(sqrtf(un2), 1e-12f);
            unsigned long long key = ~0ULL;
            if (tid < MEMN) {
                const float wun = un * us;
                g_wu[b * MEMN + tid] = wun;
                key = (((unsigned long long)__float_as_uint(wun)) << 32) | (unsigned)tid;
            }
            const unsigned long long mk = brminu(key);
            const int amin = (int)(mk & 0xffffffffu);
            if (tid < MEMN) wwnxt[b * MEMN + tid] = GATE_C * s_wr[tid] + ((tid == amin) ? OMG_C : 0.f);
            __syncthreads();
        }
    };

    // ---- phase C: M(t+1) = l2norm(M(t) + w_w(t)^T h(t)) ----
    auto phaseC = [&](const float* hcur, const float* Mcur, const float* wwcur,
                      float* Mnxt, float* MTnxt, float* Mnnxt) {
        const int cwg = w - NWG_A - NWG_B;
        for (int mi = 0; mi < 4; ++mi) {
            const int m = cwg * 4 + mi;
            if (tid < BATCH) s_wwc[tid] = wwcur[tid * MEMN + m];
            __syncthreads();
            float v = Mcur[m * HSZ + tid];
#pragma unroll 8
            for (int b = 0; b < BATCH; ++b) v += s_wwc[b] * hcur[b * HSZ + tid];
            const float nrm = sqrtf(brsum(v * v));
            const float scale = 1.0f / fmaxf(nrm, 1e-12f);
            const float vo = v * scale;
            Mnxt[m * HSZ + tid] = vo;
            MTnxt[tid * MEMN + m] = vo;
            if (tid == 0) Mnnxt[m] = nrm * scale;
            __syncthreads();
        }
    };

    int seq = 1;
    gridbar(seq); ++seq;  // init done

    if (w < NWG_A) phaseA(0, g_h[1], g_h[0]);  // h~_0
    gridbar(seq); ++seq;

    for (int t = 0; t < TSTEPS; ++t) {
        const int p = t & 1;
        const float* hcur = g_h[p];
        float* hnxt = g_h[p ^ 1];
        const float* Mcur = g_M[p];   float* Mnxt = g_M[p ^ 1];
        const float* MTcur = g_MT[p]; float* MTnxt = g_MT[p ^ 1];
        const float* Mncur = g_Mn[p]; float* Mnnxt = g_Mn[p ^ 1];
        const float* wwcur = g_ww[p]; float* wwnxt = g_ww[p ^ 1];
        if (w < NWG_A) {
            if (t < TSTEPS - 1) phaseA(t + 1, hcur, hnxt);
        } else if (w < NWG_A + NWG_B) {
            phaseB(t, hcur, Mcur, MTcur, Mncur, wwcur, wwnxt);
        } else {
            phaseC(hcur, Mcur, wwcur, Mnxt, MTnxt, Mnnxt);
        }
        gridbar(seq); ++seq;
    }
}

extern "C" void kernel_launch(void* const* d_in, const int* in_sizes, int n_in,
                              void* d_out, int out_size, void* d_ws, size_t ws_size,
                              hipStream_t stream) {
    const float* X   = (const float*)d_in[0];
    const float* Wih = (const float*)d_in[1];
    const float* Whh = (const float*)d_in[2];
    const float* bih = (const float*)d_in[3];
    const float* bhh = (const float*)d_in[4];
    float* out = (float*)d_out;
    (void)in_sizes; (void)n_in; (void)out_size; (void)d_ws; (void)ws_size;

    hipLaunchKernelGGL(reset_ctrl_kernel, dim3(1), dim3(1), 0, stream);
    hipLaunchKernelGGL(mann_persist, dim3(NWG), dim3(NTHR), 0, stream,
                       X, Wih, Whh, bih, bhh, out);
}

// Round 2
// 55916.058 us; speedup vs baseline: 1.7378x; 1.7378x over previous
//
#include <hip/hip_runtime.h>
#include <math.h>

#define BATCH 128
#define TSTEPS 1024
#define INSZ 256
#define HSZ 256
#define MEMN 128

#define NWG_A 128
#define NWG_B 64
#define NWG_C 32
#define NWG 224
#define NTHR 256

#define GATE_C 0.40131233988754794f
#define OMG_C (1.0f - GATE_C)
#define GAMMA_C 0.3f

// ---------------- persistent state (re-initialized every launch) ----------------
__device__ float g_h[2][BATCH * HSZ];    // hidden [b][j], double-buffered
__device__ float g_hT[2][HSZ * BATCH];   // hidden transposed [j][b], double-buffered
__device__ float g_c[BATCH * HSZ];       // cell state, owner-updated in place
__device__ float g_M[2][MEMN * HSZ];     // memory rows, double-buffered
__device__ float g_MT[2][HSZ * MEMN];    // memory transposed, double-buffered
__device__ float g_wu[BATCH * MEMN];     // usage weights, owner-updated in place
__device__ float g_ww[2][BATCH * MEMN];  // write weights, double-buffered
__device__ float g_Mn[2][MEMN];          // per-row memory norms, double-buffered
__device__ int g_flags[NWG * 16];        // per-WG arrival flags (64B apart)
__device__ int g_release;                // barrier release sequence

__global__ void reset_ctrl_kernel() {
    const int i = threadIdx.x;
    for (int k = i; k < NWG * 16; k += 256) g_flags[k] = 0;
    if (i == 0) g_release = 0;
}

__device__ __forceinline__ float sigf(float x) { return 1.0f / (1.0f + expf(-x)); }

#define FMA4(a, wv, xv)                                   \
    do {                                                  \
        (a).x += (wv).x * (xv).x; (a).y += (wv).y * (xv).y; \
        (a).z += (wv).z * (xv).z; (a).w += (wv).w * (xv).w; \
    } while (0)

// grid barrier: relaxed flag stores + one collector WG; exactly one acquire
// fence per WG per step (no invalidation while polling).
__device__ __forceinline__ void gridbar(int w, int tid, int seq) {
    __syncthreads();  // compiler drains vmcnt before s_barrier -> WG stores in L2
    if (w == NWG - 1) {
        if (tid == 0) {
            __builtin_amdgcn_fence(__ATOMIC_RELEASE, "agent");  // flush L2 -> MALL
            __hip_atomic_store(&g_flags[(NWG - 1) * 16], seq, __ATOMIC_RELAXED,
                               __HIP_MEMORY_SCOPE_AGENT);
        }
        if (tid < NWG) {
            while (__hip_atomic_load(&g_flags[tid * 16], __ATOMIC_RELAXED,
                                     __HIP_MEMORY_SCOPE_AGENT) < seq) {
                __builtin_amdgcn_s_sleep(1);
            }
        }
        __syncthreads();
        if (tid == 0) {
            __builtin_amdgcn_fence(__ATOMIC_ACQ_REL, "agent");  // order polls, inv caches
            __hip_atomic_store(&g_release, seq, __ATOMIC_RELAXED,
                               __HIP_MEMORY_SCOPE_AGENT);
        }
    } else {
        if (tid == 0) {
            __builtin_amdgcn_fence(__ATOMIC_RELEASE, "agent");
            __hip_atomic_store(&g_flags[w * 16], seq, __ATOMIC_RELAXED,
                               __HIP_MEMORY_SCOPE_AGENT);
            while (__hip_atomic_load(&g_release, __ATOMIC_RELAXED,
                                     __HIP_MEMORY_SCOPE_AGENT) < seq) {
                __builtin_amdgcn_s_sleep(2);
            }
            __builtin_amdgcn_fence(__ATOMIC_ACQUIRE, "agent");  // single inv per step
        }
        __syncthreads();
    }
}

__global__ void __launch_bounds__(NTHR, 1)
mann_persist(const float* __restrict__ X, const float* __restrict__ Wih,
             const float* __restrict__ Whh, const float* __restrict__ bih,
             const float* __restrict__ bhh, float* __restrict__ out) {
    // ---- LDS ----
    __shared__ float4 s_w4[1024];      // A: resident weights [8 rows][128 f4]
    __shared__ float4 s_xt[2][1024];   // A: xh k-tiles [128 b][8 chunks], swizzled
    __shared__ __align__(16) float s_h[HSZ];     // B
    __shared__ __align__(16) float s_in[MEMN];   // B
    __shared__ __align__(16) float s_wr[MEMN];   // B
    __shared__ __align__(16) float s_wwc[4 * BATCH];  // C
    __shared__ float s_red[4];
    __shared__ unsigned long long s_redu[4];

    const int w = blockIdx.x;
    const int tid = threadIdx.x;

    // ---- block reductions (all 256 threads must call) ----
    auto brsum = [&](float v) -> float {
#pragma unroll
        for (int o = 32; o; o >>= 1) v += __shfl_xor(v, o, 64);
        if ((tid & 63) == 0) s_red[tid >> 6] = v;
        __syncthreads();
        v = (s_red[0] + s_red[1]) + (s_red[2] + s_red[3]);
        __syncthreads();
        return v;
    };
    auto brmax = [&](float v) -> float {
#pragma unroll
        for (int o = 32; o; o >>= 1) v = fmaxf(v, __shfl_xor(v, o, 64));
        if ((tid & 63) == 0) s_red[tid >> 6] = v;
        __syncthreads();
        v = fmaxf(fmaxf(s_red[0], s_red[1]), fmaxf(s_red[2], s_red[3]));
        __syncthreads();
        return v;
    };
    auto brminu = [&](unsigned long long v) -> unsigned long long {
#pragma unroll
        for (int o = 32; o; o >>= 1) {
            unsigned long long o2 = __shfl_xor(v, o, 64);
            v = (o2 < v) ? o2 : v;
        }
        if ((tid & 63) == 0) s_redu[tid >> 6] = v;
        __syncthreads();
        unsigned long long a = (s_redu[0] < s_redu[1]) ? s_redu[0] : s_redu[1];
        unsigned long long b = (s_redu[2] < s_redu[3]) ? s_redu[2] : s_redu[3];
        v = (a < b) ? a : b;
        __syncthreads();
        return v;
    };

    // ---- init all state (deterministic per launch) ----
    {
        const int gt = w * NTHR + tid, gn = NWG * NTHR;
        for (int i = gt; i < BATCH * HSZ; i += gn) { g_h[1][i] = 0.f; g_c[i] = 0.f; }
        for (int i = gt; i < MEMN * HSZ; i += gn) { g_M[0][i] = 0.f; g_MT[0][i] = 0.f; }
        for (int i = gt; i < BATCH * MEMN; i += gn) {
            g_wu[i] = 0.f;
            g_ww[0][i] = ((i & (MEMN - 1)) == 0) ? OMG_C : 0.f;  // t=0: argmin(zeros)=0
        }
        for (int i = gt; i < MEMN; i += gn) g_Mn[0][i] = 0.f;
    }

    const bool isA = (w < NWG_A);
    const bool isB = (w >= NWG_A) && (w < NWG_A + NWG_B);

    // ---- phase A geometry: WG w owns j in {2w, 2w+1}; thread = (j2, b) ----
    const int j2 = (tid >> 5) & 1;
    const int bA = ((tid >> 6) << 5) | (tid & 31);  // 0..127
    const int b7 = bA & 7;
    const int jA = (w << 1) | j2;                    // only meaningful for A
    float biasA[4] = {0.f, 0.f, 0.f, 0.f};
    if (isA) {
#pragma unroll
        for (int g = 0; g < 4; ++g) {
            const int row = g * HSZ + jA;
            biasA[g] = bih[row] + bhh[row];
        }
        // resident weights: local row lr = g*2+j2 -> global row g*256 + 2w + jj2
        for (int i = tid; i < 1024; i += NTHR) {
            const int lr = i >> 7, c4 = i & 127;
            const int g = lr >> 1, jj2 = lr & 1;
            const int row = g * HSZ + (w * 2 + jj2);
            float4 v;
            if (c4 < 64) v = ((const float4*)(Wih + (size_t)row * INSZ))[c4];
            else v = ((const float4*)(Whh + (size_t)row * HSZ))[c4 - 64];
            s_w4[i] = v;
        }
    }

    // ---- phase A tile helpers ----
    float4 pfA[4], pfB[4];  // register prefetch buffers (static-indexed only)

    auto loadTile = [&](int t, int ti, float4 (&pf)[4], const float* hprev) {
        const int kb = ti * 32;
#pragma unroll
        for (int q = 0; q < 4; ++q) {
            const int id = q * 256 + tid;
            const int bb = id >> 3, cc = id & 7;
            const int k = kb + cc * 4;
            const float* src = (k < INSZ)
                ? (X + ((size_t)bb * TSTEPS + t) * INSZ + k)
                : (hprev + bb * HSZ + (k - INSZ));
            pf[q] = *(const float4*)src;
        }
    };
    auto writeTile = [&](float4 (&pf)[4], float4* buf) {
#pragma unroll
        for (int q = 0; q < 4; ++q) {
            const int id = q * 256 + tid;
            const int bb = id >> 3, cc = id & 7;
            buf[(bb << 3) | (cc ^ (bb & 7))] = pf[q];  // XOR swizzle
        }
    };
    auto computeTile = [&](int i, const float4* buf, float4 (&az)[4]) {
        const int k8 = i * 8;
#pragma unroll
        for (int c = 0; c < 8; ++c) {
            const float4 xv = buf[(bA << 3) | (c ^ b7)];
#pragma unroll
            for (int g = 0; g < 4; ++g) {
                const float4 wv = s_w4[(g * 2 + j2) * 128 + k8 + c];
                FMA4(az[g], wv, xv);
            }
        }
    };
    // prefetch X-only tiles 0..2 for step t (safe before barrier: no h dependency)
    auto preA = [&](int t) {
        loadTile(t, 0, pfA, g_h[1]);
        loadTile(t, 1, pfB, g_h[1]);
        writeTile(pfA, s_xt[0]);
        loadTile(t, 2, pfA, g_h[1]);
    };
    auto mainA = [&](int t, const float* hprev, float* hout, float* hToutT) {
        float4 az[4];
#pragma unroll
        for (int g = 0; g < 4; ++g) az[g] = make_float4(0.f, 0.f, 0.f, 0.f);
        // entry: tile0 in s_xt[0] (synced by gridbar), pfB=tile1, pfA=tile2
        for (int ii = 0; ii < 8; ++ii) {
            const int i0 = 2 * ii;
            // i = i0 (even): compute s_xt[0]
            writeTile(pfB, s_xt[1]);                       // tile i0+1
            if (i0 + 3 <= 15) loadTile(t, i0 + 3, pfB, hprev);
            computeTile(i0, s_xt[0], az);
            __syncthreads();
            // i = i0+1 (odd): compute s_xt[1]
            if (i0 + 2 <= 15) writeTile(pfA, s_xt[0]);     // tile i0+2
            if (i0 + 4 <= 15) loadTile(t, i0 + 4, pfA, hprev);
            computeTile(i0 + 1, s_xt[1], az);
            __syncthreads();
        }
        float z[4];
#pragma unroll
        for (int g = 0; g < 4; ++g)
            z[g] = ((az[g].x + az[g].y) + (az[g].z + az[g].w)) + biasA[g];
        const int idx = bA * HSZ + jA;
        const float cold = g_c[idx];
        const float cn = sigf(z[1]) * cold + sigf(z[0]) * tanhf(z[2]);
        const float hn = sigf(z[3]) * tanhf(cn);
        g_c[idx] = cn;
        hout[idx] = hn;
        hToutT[jA * BATCH + bA] = hn;
    };

    // ---- phase B: read head + output + w_u/w_w update for step t ----
    auto phaseB = [&](int t, const float* hcur, const float* Mcur, const float* MTcur,
                      const float* Mncur, const float* wwcur, float* wwnxt) {
        const int bwg = w - NWG_A;
        for (int bi = 0; bi < 2; ++bi) {
            const int b = bwg * 2 + bi;
            const float hv = hcur[b * HSZ + tid];
            s_h[tid] = hv;
            __syncthreads();
            const float hnorm = sqrtf(brsum(hv * hv));
            {   // inner[m] = h . M[m], 2 threads per m (k-halves), vectorized
                const int m = tid >> 1, hf2 = tid & 1;
                const float4* mrow = (const float4*)(Mcur + (size_t)m * HSZ + hf2 * 128);
                const float4* hh4 = (const float4*)(s_h + hf2 * 128);
                float4 a4 = make_float4(0.f, 0.f, 0.f, 0.f);
#pragma unroll 8
                for (int c = 0; c < 32; ++c) {
                    const float4 mv = mrow[c], xv = hh4[c];
                    FMA4(a4, mv, xv);
                }
                float acc = (a4.x + a4.y) + (a4.z + a4.w);
                acc += __shfl_xor(acc, 1, 64);
                if (hf2 == 0) s_in[m] = acc;
            }
            __syncthreads();
            float sc = -1e30f;
            if (tid < MEMN) sc = s_in[tid] / (hnorm * Mncur[tid] + 1e-8f);
            const float mx = brmax(sc);
            const float ev = (tid < MEMN) ? expf(sc - mx) : 0.f;
            const float es = brsum(ev);
            const float wr = ev / es;
            if (tid < MEMN) s_wr[tid] = wr;
            __syncthreads();
            float4 r4 = make_float4(0.f, 0.f, 0.f, 0.f);
            {   // read vector: rd[j] = sum_m wr[m] * MT[j][m], contiguous b128
                const float4* mtj = (const float4*)(MTcur + (size_t)tid * MEMN);
                const float4* wr4 = (const float4*)s_wr;
#pragma unroll 8
                for (int c = 0; c < 32; ++c) {
                    const float4 mv = mtj[c], wv = wr4[c];
                    FMA4(r4, mv, wv);
                }
            }
            float* op = out + ((size_t)b * TSTEPS + t) * (2 * HSZ);
            op[tid] = hv;
            op[HSZ + tid] = (r4.x + r4.y) + (r4.z + r4.w);
            // w_u(t+1) = l2norm(gamma*w_u + w_r + w_w); then w_w(t+1) from argmin
            float un = 0.f;
            if (tid < MEMN) un = GAMMA_C * g_wu[b * MEMN + tid] + wr + wwcur[b * MEMN + tid];
            const float un2 = brsum(un * un);
            const float us = 1.0f / fmaxf(sqrtf(un2), 1e-12f);
            unsigned long long key = ~0ULL;
            if (tid < MEMN) {
                const float wun = un * us;
                g_wu[b * MEMN + tid] = wun;
                key = (((unsigned long long)__float_as_uint(wun)) << 32) | (unsigned)tid;
            }
            const unsigned long long mk = brminu(key);
            const int amin = (int)(mk & 0xffffffffu);
            if (tid < MEMN) wwnxt[b * MEMN + tid] = GATE_C * s_wr[tid] + ((tid == amin) ? OMG_C : 0.f);
            __syncthreads();
        }
    };

    // ---- phase C: M(t+1) = l2norm(M(t) + w_w(t)^T h(t)), via hT rows ----
    auto phaseC = [&](const float* hTcur, const float* Mcur, const float* wwcur,
                      float* Mnxt, float* MTnxt, float* Mnnxt) {
        const int m0 = (w - NWG_A - NWG_B) * 4;
        for (int i = tid; i < 4 * BATCH; i += NTHR) {
            const int mi = i >> 7, bb = i & 127;
            s_wwc[mi * BATCH + bb] = wwcur[bb * MEMN + m0 + mi];
        }
        __syncthreads();
        float acc[4];
#pragma unroll
        for (int mi = 0; mi < 4; ++mi) acc[mi] = Mcur[(size_t)(m0 + mi) * HSZ + tid];
        const float4* ht4 = (const float4*)(hTcur + (size_t)tid * BATCH);
#pragma unroll 2
        for (int cb = 0; cb < 4; ++cb) {
            float4 hb[8];
#pragma unroll
            for (int q = 0; q < 8; ++q) hb[q] = ht4[cb * 8 + q];
#pragma unroll
            for (int mi = 0; mi < 4; ++mi) {
                const float4* wc4 = ((const float4*)(s_wwc + mi * BATCH)) + cb * 8;
                float s = 0.f;
#pragma unroll
                for (int q = 0; q < 8; ++q) {
                    const float4 wv = wc4[q], hv = hb[q];
                    s += hv.x * wv.x + hv.y * wv.y + hv.z * wv.z + hv.w * wv.w;
                }
                acc[mi] += s;
            }
        }
#pragma unroll
        for (int mi = 0; mi < 4; ++mi) {
            const float nrm = sqrtf(brsum(acc[mi] * acc[mi]));
            const float scale = 1.0f / fmaxf(nrm, 1e-12f);
            const float vo = acc[mi] * scale;
            Mnxt[(size_t)(m0 + mi) * HSZ + tid] = vo;
            MTnxt[(size_t)tid * MEMN + m0 + mi] = vo;
            if (tid == 0) Mnnxt[m0 + mi] = nrm * scale;
        }
        __syncthreads();
    };

    // ---- time loop ----
    int seq = 1;
    if (isA) preA(0);
    gridbar(w, tid, seq); ++seq;  // init visible

    if (isA) { mainA(0, g_h[1], g_h[0], g_hT[0]); preA(1); }
    gridbar(w, tid, seq); ++seq;

    for (int t = 0; t < TSTEPS; ++t) {
        const int p = t & 1;
        if (isA) {
            if (t < TSTEPS - 1) {
                mainA(t + 1, g_h[p], g_h[p ^ 1], g_hT[p ^ 1]);
                if (t + 2 <= TSTEPS - 1) preA(t + 2);
            }
        } else if (isB) {
            phaseB(t, g_h[p], g_M[p], g_MT[p], g_Mn[p], g_ww[p], g_ww[p ^ 1]);
        } else {
            phaseC(g_hT[p], g_M[p], g_ww[p], g_M[p ^ 1], g_MT[p ^ 1], g_Mn[p ^ 1]);
        }
        gridbar(w, tid, seq); ++seq;
    }
}

extern "C" void kernel_launch(void* const* d_in, const int* in_sizes, int n_in,
                              void* d_out, int out_size, void* d_ws, size_t ws_size,
                              hipStream_t stream) {
    const float* X   = (const float*)d_in[0];
    const float* Wih = (const float*)d_in[1];
    const float* Whh = (const float*)d_in[2];
    const float* bih = (const float*)d_in[3];
    const float* bhh = (const float*)d_in[4];
    float* out = (float*)d_out;
    (void)in_sizes; (void)n_in; (void)out_size; (void)d_ws; (void)ws_size;

    hipLaunchKernelGGL(reset_ctrl_kernel, dim3(1), dim3(256), 0, stream);
    hipLaunchKernelGGL(mann_persist, dim3(NWG), dim3(NTHR), 0, stream,
                       X, Wih, Whh, bih, bhh, out);
}

// Round 3
// 27386.252 us; speedup vs baseline: 3.5483x; 2.0418x over previous
//
#include <hip/hip_runtime.h>
#include <math.h>

#define BATCH 128
#define TSTEPS 1024
#define INSZ 256
#define HSZ 256
#define MEMN 128

#define NWG_A 128
#define NWG_B 64
#define NWG_C 32
#define NWG 224
#define NTHR 256

#define GATE_C 0.40131233988754794f
#define OMG_C  (1.0f - GATE_C)
#define GAMMA_C 0.3f

// ---- per-step state, unique slot per t (write-through produced, cached-read consumed) ----
__device__ float g_hT[(size_t)TSTEPS * HSZ * BATCH];   // hT(t)[j][b]
__device__ float g_M [(size_t)TSTEPS * MEMN * HSZ];    // M(t)[m][j], slots 1..1023
__device__ float g_Mn[(size_t)TSTEPS * MEMN];          // Mn(t)[m],  slots 1..1023
__device__ float g_ww[(size_t)TSTEPS * BATCH * MEMN];  // ww(t)[b][m], slots 1..1023
__device__ float g_c[BATCH * HSZ];                     // private per A-thread (cached)
__device__ int g_cA[TSTEPS];
__device__ int g_cB[TSTEPS];
__device__ int g_cC[TSTEPS];
__device__ int g_abort;

__global__ void reset_ctrl_kernel() {
    const int i = threadIdx.x;
    for (int k = i; k < TSTEPS; k += 256) {
        __hip_atomic_store(&g_cA[k], 0, __ATOMIC_RELAXED, __HIP_MEMORY_SCOPE_AGENT);
        __hip_atomic_store(&g_cB[k], 0, __ATOMIC_RELAXED, __HIP_MEMORY_SCOPE_AGENT);
        __hip_atomic_store(&g_cC[k], 0, __ATOMIC_RELAXED, __HIP_MEMORY_SCOPE_AGENT);
    }
    if (i == 0) __hip_atomic_store(&g_abort, 0, __ATOMIC_RELAXED, __HIP_MEMORY_SCOPE_AGENT);
}

__device__ __forceinline__ float sigf(float x) { return 1.0f / (1.0f + expf(-x)); }

__device__ __forceinline__ void st_wt(float* p, float v) {
    __hip_atomic_store(p, v, __ATOMIC_RELAXED, __HIP_MEMORY_SCOPE_AGENT);
}
__device__ __forceinline__ void wait_vm0() { asm volatile("s_waitcnt vmcnt(0)" ::: "memory"); }
__device__ __forceinline__ void signal(int* cnt) {
    __hip_atomic_fetch_add(cnt, 1, __ATOMIC_RELAXED, __HIP_MEMORY_SCOPE_AGENT);
}
__device__ __forceinline__ void pollcnt(int* cnt, int want) {
    int it = 0;
    while (__hip_atomic_load(cnt, __ATOMIC_RELAXED, __HIP_MEMORY_SCOPE_AGENT) < want) {
        __builtin_amdgcn_s_sleep(2);
        if ((++it & 255) == 0) {
            if (it > (1 << 21)) {
                __hip_atomic_store(&g_abort, 1, __ATOMIC_RELAXED, __HIP_MEMORY_SCOPE_AGENT);
                break;
            }
            if (__hip_atomic_load(&g_abort, __ATOMIC_RELAXED, __HIP_MEMORY_SCOPE_AGENT)) break;
        }
    }
}

__global__ void __launch_bounds__(NTHR, 1)
mann_persist(const float* __restrict__ X, const float* __restrict__ Wih,
             const float* __restrict__ Whh, const float* __restrict__ bih,
             const float* __restrict__ bhh, float* __restrict__ out) {
    __shared__ float4 s_x4[64 * 128];   // A: xh [b][k4g] XOR-swizzled (128 KB)
    __shared__ float s_aux[4096];       // A: partials (16 KB); B/C carve
    __shared__ float s_red8[8];
    __shared__ unsigned long long s_redu8[8];

    const int w = blockIdx.x, tid = threadIdx.x;
    const int lane = tid & 63, wv = tid >> 6;

    // ---- reductions ----
    auto red256sum = [&](float v) -> float {
#pragma unroll
        for (int o = 32; o; o >>= 1) v += __shfl_xor(v, o, 64);
        if (lane == 0) s_red8[wv] = v;
        __syncthreads();
        float r = (s_red8[0] + s_red8[1]) + (s_red8[2] + s_red8[3]);
        __syncthreads();
        return r;
    };
    auto grpsum = [&](float v) -> float {
#pragma unroll
        for (int o = 32; o; o >>= 1) v += __shfl_xor(v, o, 64);
        if (lane == 0) s_red8[wv] = v;
        __syncthreads();
        float r = s_red8[(tid >> 7) * 2] + s_red8[(tid >> 7) * 2 + 1];
        __syncthreads();
        return r;
    };
    auto grpmax = [&](float v) -> float {
#pragma unroll
        for (int o = 32; o; o >>= 1) v = fmaxf(v, __shfl_xor(v, o, 64));
        if (lane == 0) s_red8[wv] = v;
        __syncthreads();
        float r = fmaxf(s_red8[(tid >> 7) * 2], s_red8[(tid >> 7) * 2 + 1]);
        __syncthreads();
        return r;
    };
    auto grpminu = [&](unsigned long long v) -> unsigned long long {
#pragma unroll
        for (int o = 32; o; o >>= 1) {
            unsigned long long o2 = __shfl_xor(v, o, 64);
            v = (o2 < v) ? o2 : v;
        }
        if (lane == 0) s_redu8[wv] = v;
        __syncthreads();
        unsigned long long a = s_redu8[(tid >> 7) * 2], b2 = s_redu8[(tid >> 7) * 2 + 1];
        unsigned long long r = (a < b2) ? a : b2;
        __syncthreads();
        return r;
    };

    if (w < NWG_A) {
        // ================= phase A: LSTM cell =================
        const int bb = w >> 6, jb = w & 63;
        const int bglob = bb * 64 + lane;
        float biasA[4];
#pragma unroll
        for (int g = 0; g < 4; ++g) {
            const int row = g * HSZ + jb * 4 + wv;
            biasA[g] = bih[row] + bhh[row];
        }

        auto stageX = [&](int t) {
            const int kq = tid & 63, bofs = tid >> 6;
#pragma unroll 4
            for (int rep = 0; rep < 16; ++rep) {
                const int b = rep * 4 + bofs;
                const float4 v = *(const float4*)(X + ((size_t)(bb * 64 + b) * TSTEPS + t) * INSZ + kq * 4);
                s_x4[b * 128 + (kq ^ (b & 7))] = v;
            }
        };
        auto computeRegion = [&](float (&acc)[16], const float* __restrict__ Wb, const int kofs) {
            const int kbase = kofs + wv * 64;
#pragma unroll 4
            for (int k4 = 0; k4 < 16; ++k4) {
                const int kg = kbase + k4 * 4;
                const float4 xv = s_x4[lane * 128 + ((kg >> 2) ^ (lane & 7))];
                const int kl = kg - kofs;
#pragma unroll
                for (int rr = 0; rr < 16; ++rr) {
                    const int grow = (rr >> 2) * HSZ + jb * 4 + (rr & 3);
                    const float4 wv4 = *(const float4*)(Wb + (size_t)grow * 256 + kl);
                    acc[rr] += wv4.x * xv.x + wv4.y * xv.y + wv4.z * xv.z + wv4.w * xv.w;
                }
            }
        };

        stageX(0);
        __syncthreads();

        for (int t = 0; t < TSTEPS; ++t) {
            float acc[16];
#pragma unroll
            for (int i = 0; i < 16; ++i) acc[i] = 0.f;
            float4 hv[16];
            if (t > 0) {
                if (tid == 0) pollcnt(&g_cA[t - 1], NWG_A);
                __syncthreads();
                asm volatile("" ::: "memory");
                // issue h(t-1) gather (64 coalesced scalar loads) — lands during X compute
#pragma unroll
                for (int rep = 0; rep < 16; ++rep) {
                    const int j0 = (wv * 16 + rep) * 4;
                    const size_t base = ((size_t)(t - 1) * HSZ + j0) * BATCH + bglob;
                    float4 v;
                    v.x = g_hT[base];
                    v.y = g_hT[base + BATCH];
                    v.z = g_hT[base + 2 * BATCH];
                    v.w = g_hT[base + 3 * BATCH];
                    hv[rep] = v;
                }
            }
            computeRegion(acc, Wih, 0);
            if (t > 0) {
#pragma unroll
                for (int rep = 0; rep < 16; ++rep)
                    s_x4[lane * 128 + ((64 + wv * 16 + rep) ^ (lane & 7))] = hv[rep];
            } else {
                const float4 z4 = make_float4(0.f, 0.f, 0.f, 0.f);
#pragma unroll
                for (int rep = 0; rep < 16; ++rep)
                    s_x4[lane * 128 + ((64 + wv * 16 + rep) ^ (lane & 7))] = z4;
            }
            __syncthreads();
            computeRegion(acc, Whh, 256);
#pragma unroll
            for (int rr = 0; rr < 16; ++rr) s_aux[(wv * 16 + rr) * 64 + lane] = acc[rr];
            __syncthreads();
            float z[4];
#pragma unroll
            for (int g = 0; g < 4; ++g) {
                const int rr = g * 4 + wv;
                z[g] = ((s_aux[rr * 64 + lane] + s_aux[(16 + rr) * 64 + lane]) +
                        (s_aux[(32 + rr) * 64 + lane] + s_aux[(48 + rr) * 64 + lane])) + biasA[g];
            }
            const int jglob = jb * 4 + wv;
            const int cidx = bglob * HSZ + jglob;
            const float cold = (t == 0) ? 0.f : g_c[cidx];
            const float cn = sigf(z[1]) * cold + sigf(z[0]) * tanhf(z[2]);
            const float hn = sigf(z[3]) * tanhf(cn);
            g_c[cidx] = cn;
            st_wt(&g_hT[((size_t)t * HSZ + jglob) * BATCH + bglob], hn);
            wait_vm0();
            __syncthreads();
            if (tid == 0) signal(&g_cA[t]);
            if (t + 1 < TSTEPS) stageX(t + 1);
        }
    } else if (w < NWG_A + NWG_B) {
        // ================= phase B: read head + output + w_u/w_w =================
        const int bwg = w - NWG_A;
        const int grp = tid >> 7, lm = tid & 127;
        const int bB = bwg * 2 + grp;
        float* s_h2 = s_aux;          // [2][256]
        float* s_wr2 = s_aux + 512;   // [2][128]
        float wwreg = (lm == 0) ? OMG_C : 0.f;
        float wureg = 0.f;

        for (int t = 0; t < TSTEPS; ++t) {
            if (tid == 0) {
                pollcnt(&g_cA[t], NWG_A);
                if (t > 0) pollcnt(&g_cC[t - 1], NWG_C);
            }
            __syncthreads();
            asm volatile("" ::: "memory");
            s_h2[grp * 256 + lm] = g_hT[((size_t)t * HSZ + lm) * BATCH + bB];
            s_h2[grp * 256 + lm + 128] = g_hT[((size_t)t * HSZ + lm + 128) * BATCH + bB];
            __syncthreads();
            const float hv0 = s_h2[grp * 256 + lm], hv1 = s_h2[grp * 256 + lm + 128];
            const float hnorm = sqrtf(grpsum(hv0 * hv0 + hv1 * hv1));
            float sc = 0.f;
            if (t > 0) {
                const float4* mrow = (const float4*)&g_M[((size_t)t * MEMN + lm) * HSZ];
                const float4* h4 = (const float4*)&s_h2[grp * 256];
                float a = 0.f;
#pragma unroll 8
                for (int c = 0; c < 64; ++c) {
                    const float4 m4 = mrow[c], x4 = h4[c];
                    a += m4.x * x4.x + m4.y * x4.y + m4.z * x4.z + m4.w * x4.w;
                }
                const float mn = g_Mn[(size_t)t * MEMN + lm];
                sc = a / (hnorm * mn + 1e-8f);
            }
            const float mx = grpmax(sc);
            const float ev = expf(sc - mx);
            const float es = grpsum(ev);
            const float wr = ev / es;
            s_wr2[grp * 128 + lm] = wr;
            __syncthreads();
            float rd0 = 0.f, rd1 = 0.f;
            if (t > 0) {
#pragma unroll 8
                for (int m = 0; m < 128; ++m) {
                    const float mv = g_M[((size_t)t * MEMN + m) * HSZ + tid];
                    rd0 += s_wr2[m] * mv;
                    rd1 += s_wr2[128 + m] * mv;
                }
            }
            const int b0 = bwg * 2, b1 = b0 + 1;
            float* o0 = out + ((size_t)b0 * TSTEPS + t) * 512;
            float* o1 = out + ((size_t)b1 * TSTEPS + t) * 512;
            o0[tid] = s_h2[tid];
            o1[tid] = s_h2[256 + tid];
            o0[256 + tid] = rd0;
            o1[256 + tid] = rd1;
            // w_u(t+1) = l2norm(gamma*w_u + w_r + w_w(t)); w_w(t+1) from argmin
            const float un = GAMMA_C * wureg + wr + wwreg;
            const float un2 = grpsum(un * un);
            const float us = 1.0f / fmaxf(sqrtf(un2), 1e-12f);
            const float wun = un * us;
            wureg = wun;
            unsigned long long key =
                (((unsigned long long)__float_as_uint(wun)) << 32) | (unsigned)lm;
            const unsigned long long mk = grpminu(key);
            const int amin = (int)(mk & 0xffffffffu);
            const float wwn = GATE_C * wr + ((lm == amin) ? OMG_C : 0.f);
            wwreg = wwn;
            if (t + 1 < TSTEPS)
                st_wt(&g_ww[((size_t)(t + 1) * BATCH + bB) * MEMN + lm], wwn);
            wait_vm0();
            __syncthreads();
            if (tid == 0) signal(&g_cB[t]);
        }
    } else {
        // ================= phase C: M(t+1) = l2norm(M(t) + ww(t)^T h(t)) =================
        const int cwg = w - NWG_A - NWG_B;
        const int m0 = cwg * 4;
        float* s_wwc = s_aux;  // [4][128]

        for (int t = 0; t < TSTEPS - 1; ++t) {
            if (tid == 0) {
                if (t > 0) pollcnt(&g_cB[t - 1], NWG_B);
                pollcnt(&g_cA[t], NWG_A);
            }
            __syncthreads();
            asm volatile("" ::: "memory");
#pragma unroll
            for (int e = tid; e < 512; e += 256) {
                const int mi = e & 3, b = e >> 2;
                float v;
                if (t > 0) v = g_ww[((size_t)t * BATCH + b) * MEMN + m0 + mi];
                else v = (m0 + mi == 0) ? OMG_C : 0.f;
                s_wwc[mi * 128 + b] = v;
            }
            __syncthreads();
            float macc[4];
#pragma unroll
            for (int mi = 0; mi < 4; ++mi)
                macc[mi] = (t > 0) ? g_M[((size_t)t * MEMN + m0 + mi) * HSZ + tid] : 0.f;
            const float4* ht4 = (const float4*)&g_hT[((size_t)t * HSZ + tid) * BATCH];
#pragma unroll 4
            for (int b4 = 0; b4 < 32; ++b4) {
                const float4 hv4 = ht4[b4];
#pragma unroll
                for (int mi = 0; mi < 4; ++mi) {
                    const float* wc = &s_wwc[mi * 128 + b4 * 4];
                    macc[mi] += wc[0] * hv4.x + wc[1] * hv4.y + wc[2] * hv4.z + wc[3] * hv4.w;
                }
            }
#pragma unroll
            for (int mi = 0; mi < 4; ++mi) {
                const float nrm = sqrtf(red256sum(macc[mi] * macc[mi]));
                const float scale = 1.0f / fmaxf(nrm, 1e-12f);
                const float vo = macc[mi] * scale;
                st_wt(&g_M[((size_t)(t + 1) * MEMN + m0 + mi) * HSZ + tid], vo);
                if (tid == 0) st_wt(&g_Mn[(size_t)(t + 1) * MEMN + m0 + mi], nrm * scale);
            }
            wait_vm0();
            __syncthreads();
            if (tid == 0) signal(&g_cC[t]);
        }
    }
}

extern "C" void kernel_launch(void* const* d_in, const int* in_sizes, int n_in,
                              void* d_out, int out_size, void* d_ws, size_t ws_size,
                              hipStream_t stream) {
    const float* X   = (const float*)d_in[0];
    const float* Wih = (const float*)d_in[1];
    const float* Whh = (const float*)d_in[2];
    const float* bih = (const float*)d_in[3];
    const float* bhh = (const float*)d_in[4];
    float* out = (float*)d_out;
    (void)in_sizes; (void)n_in; (void)out_size; (void)d_ws; (void)ws_size;

    hipLaunchKernelGGL(reset_ctrl_kernel, dim3(1), dim3(256), 0, stream);
    hipLaunchKernelGGL(mann_persist, dim3(NWG), dim3(NTHR), 0, stream,
                       X, Wih, Whh, bih, bhh, out);
}

// Round 4
// 24044.853 us; speedup vs baseline: 4.0413x; 1.1390x over previous
//
#include <hip/hip_runtime.h>
#include <math.h>

#define BATCH 128
#define TSTEPS 1024
#define INSZ 256
#define HSZ 256
#define MEMN 128

#define NWG_A 128
#define NWG_B 64
#define NWG_C 32
#define NWG 224
#define NTHR 256

#define GATE_C 0.40131233988754794f
#define OMG_C  (1.0f - GATE_C)
#define GAMMA_C 0.3f

// ---- per-step state, unique slot per t (write-through produced, cached-read consumed) ----
__device__ float g_hT[(size_t)TSTEPS * HSZ * BATCH];   // hT(t)[j][b]
__device__ float g_M [(size_t)TSTEPS * MEMN * HSZ];    // M(t)[m][j], slots 1..1023
__device__ float g_Mn[(size_t)TSTEPS * MEMN];          // Mn(t)[m],  slots 1..1023
__device__ float g_ww[(size_t)TSTEPS * BATCH * MEMN];  // ww(t)[b][m], slots 1..1023
__device__ float g_c[BATCH * HSZ];                     // private per A-thread (cached)
// ---- per-WG completion flags: NO RMWs anywhere (plain bypass stores + scans) ----
__device__ int g_fA[TSTEPS * NWG_A];
__device__ int g_fB[TSTEPS * NWG_B];
__device__ int g_fC[TSTEPS * NWG_C];

__global__ void reset_ctrl_kernel() {
    const int gt = blockIdx.x * 256 + threadIdx.x, gn = gridDim.x * 256;
    for (int i = gt; i < TSTEPS * NWG_A; i += gn)
        __hip_atomic_store(&g_fA[i], 0, __ATOMIC_RELAXED, __HIP_MEMORY_SCOPE_AGENT);
    for (int i = gt; i < TSTEPS * NWG_B; i += gn)
        __hip_atomic_store(&g_fB[i], 0, __ATOMIC_RELAXED, __HIP_MEMORY_SCOPE_AGENT);
    for (int i = gt; i < TSTEPS * NWG_C; i += gn)
        __hip_atomic_store(&g_fC[i], 0, __ATOMIC_RELAXED, __HIP_MEMORY_SCOPE_AGENT);
}

__device__ __forceinline__ float sigf(float x) { return 1.0f / (1.0f + expf(-x)); }

__device__ __forceinline__ void st_wt(float* p, float v) {
    __hip_atomic_store(p, v, __ATOMIC_RELAXED, __HIP_MEMORY_SCOPE_AGENT);
}
__device__ __forceinline__ void st_flag(int* p, int v) {
    __hip_atomic_store(p, v, __ATOMIC_RELAXED, __HIP_MEMORY_SCOPE_AGENT);
}
__device__ __forceinline__ void wait_vm0() { asm volatile("s_waitcnt vmcnt(0)" ::: "memory"); }

// wave-cooperative flag scan: each lane checks n/64 slots; no RMW, no shared-line RMW queueing
__device__ __forceinline__ void wait_flags(int* f, int n, int want, int lane) {
    int it = 0;
    for (;;) {
        bool ok = true;
        for (int i = lane; i < n; i += 64)
            ok &= (__hip_atomic_load(&f[i], __ATOMIC_RELAXED, __HIP_MEMORY_SCOPE_AGENT) == want);
        if (__all(ok)) break;
        __builtin_amdgcn_s_sleep(1);
        if (++it > (1 << 22)) break;  // hang valve (deterministic-failure, not deadlock)
    }
}

__global__ void __launch_bounds__(NTHR, 1)
mann_persist(const float* __restrict__ X, const float* __restrict__ Wih,
             const float* __restrict__ Whh, const float* __restrict__ bih,
             const float* __restrict__ bhh, float* __restrict__ out) {
    __shared__ float4 s_x4[64 * 128];   // A: xh [b][k4g] XOR-swizzled (128 KB)
    __shared__ float s_aux[4096];       // A: partials (16 KB); B/C carve
    __shared__ float s_red8[8];
    __shared__ unsigned long long s_redu8[8];

    const int w = blockIdx.x, tid = threadIdx.x;
    const int lane = tid & 63, wv = tid >> 6;

    // ---- reductions ----
    auto red256sum = [&](float v) -> float {
#pragma unroll
        for (int o = 32; o; o >>= 1) v += __shfl_xor(v, o, 64);
        if (lane == 0) s_red8[wv] = v;
        __syncthreads();
        float r = (s_red8[0] + s_red8[1]) + (s_red8[2] + s_red8[3]);
        __syncthreads();
        return r;
    };
    auto grpsum = [&](float v) -> float {
#pragma unroll
        for (int o = 32; o; o >>= 1) v += __shfl_xor(v, o, 64);
        if (lane == 0) s_red8[wv] = v;
        __syncthreads();
        float r = s_red8[(tid >> 7) * 2] + s_red8[(tid >> 7) * 2 + 1];
        __syncthreads();
        return r;
    };
    auto grpmax = [&](float v) -> float {
#pragma unroll
        for (int o = 32; o; o >>= 1) v = fmaxf(v, __shfl_xor(v, o, 64));
        if (lane == 0) s_red8[wv] = v;
        __syncthreads();
        float r = fmaxf(s_red8[(tid >> 7) * 2], s_red8[(tid >> 7) * 2 + 1]);
        __syncthreads();
        return r;
    };
    auto grpminu = [&](unsigned long long v) -> unsigned long long {
#pragma unroll
        for (int o = 32; o; o >>= 1) {
            unsigned long long o2 = __shfl_xor(v, o, 64);
            v = (o2 < v) ? o2 : v;
        }
        if (lane == 0) s_redu8[wv] = v;
        __syncthreads();
        unsigned long long a = s_redu8[(tid >> 7) * 2], b2 = s_redu8[(tid >> 7) * 2 + 1];
        unsigned long long r = (a < b2) ? a : b2;
        __syncthreads();
        return r;
    };

    if (w < NWG_A) {
        // ================= phase A: LSTM cell =================
        const int bb = w >> 6, jb = w & 63;
        const int bglob = bb * 64 + lane;
        float biasA[4];
#pragma unroll
        for (int g = 0; g < 4; ++g) {
            const int row = g * HSZ + jb * 4 + wv;
            biasA[g] = bih[row] + bhh[row];
        }

        auto stageX = [&](int t) {
            const int kq = tid & 63, bofs = tid >> 6;
#pragma unroll 4
            for (int rep = 0; rep < 16; ++rep) {
                const int b = rep * 4 + bofs;
                const float4 v = *(const float4*)(X + ((size_t)(bb * 64 + b) * TSTEPS + t) * INSZ + kq * 4);
                s_x4[b * 128 + (kq ^ (b & 7))] = v;
            }
        };
        auto computeRegion = [&](float (&acc)[16], const float* __restrict__ Wb, const int kofs) {
            const int kbase = kofs + wv * 64;
#pragma unroll 4
            for (int k4 = 0; k4 < 16; ++k4) {
                const int kg = kbase + k4 * 4;
                const float4 xv = s_x4[lane * 128 + ((kg >> 2) ^ (lane & 7))];
                const int kl = kg - kofs;
#pragma unroll
                for (int rr = 0; rr < 16; ++rr) {
                    const int grow = (rr >> 2) * HSZ + jb * 4 + (rr & 3);
                    const float4 wv4 = *(const float4*)(Wb + (size_t)grow * 256 + kl);
                    acc[rr] += wv4.x * xv.x + wv4.y * xv.y + wv4.z * xv.z + wv4.w * xv.w;
                }
            }
        };

        stageX(0);
        __syncthreads();

        for (int t = 0; t < TSTEPS; ++t) {
            float acc[16];
#pragma unroll
            for (int i = 0; i < 16; ++i) acc[i] = 0.f;
            float4 hv[16];
            if (t > 0) {
                if (wv == 0) wait_flags(g_fA + (size_t)(t - 1) * NWG_A, NWG_A, t, lane);
                __syncthreads();
                asm volatile("" ::: "memory");
                // issue h(t-1) gather (64 coalesced scalar loads) — lands during X compute
#pragma unroll
                for (int rep = 0; rep < 16; ++rep) {
                    const int j0 = (wv * 16 + rep) * 4;
                    const size_t base = ((size_t)(t - 1) * HSZ + j0) * BATCH + bglob;
                    float4 v;
                    v.x = g_hT[base];
                    v.y = g_hT[base + BATCH];
                    v.z = g_hT[base + 2 * BATCH];
                    v.w = g_hT[base + 3 * BATCH];
                    hv[rep] = v;
                }
            }
            computeRegion(acc, Wih, 0);
            if (t > 0) {
#pragma unroll
                for (int rep = 0; rep < 16; ++rep)
                    s_x4[lane * 128 + ((64 + wv * 16 + rep) ^ (lane & 7))] = hv[rep];
            } else {
                const float4 z4 = make_float4(0.f, 0.f, 0.f, 0.f);
#pragma unroll
                for (int rep = 0; rep < 16; ++rep)
                    s_x4[lane * 128 + ((64 + wv * 16 + rep) ^ (lane & 7))] = z4;
            }
            __syncthreads();
            computeRegion(acc, Whh, 256);
#pragma unroll
            for (int rr = 0; rr < 16; ++rr) s_aux[(wv * 16 + rr) * 64 + lane] = acc[rr];
            __syncthreads();
            float z[4];
#pragma unroll
            for (int g = 0; g < 4; ++g) {
                const int rr = g * 4 + wv;
                z[g] = ((s_aux[rr * 64 + lane] + s_aux[(16 + rr) * 64 + lane]) +
                        (s_aux[(32 + rr) * 64 + lane] + s_aux[(48 + rr) * 64 + lane])) + biasA[g];
            }
            const int jglob = jb * 4 + wv;
            const int cidx = bglob * HSZ + jglob;
            const float cold = (t == 0) ? 0.f : g_c[cidx];
            const float cn = sigf(z[1]) * cold + sigf(z[0]) * tanhf(z[2]);
            const float hn = sigf(z[3]) * tanhf(cn);
            g_c[cidx] = cn;
            st_wt(&g_hT[((size_t)t * HSZ + jglob) * BATCH + bglob], hn);
            wait_vm0();
            __syncthreads();
            if (tid == 0) st_flag(&g_fA[(size_t)t * NWG_A + w], t + 1);
            if (t + 1 < TSTEPS) stageX(t + 1);
        }
    } else if (w < NWG_A + NWG_B) {
        // ================= phase B: read head + output + w_u/w_w =================
        const int bwg = w - NWG_A;
        const int grp = tid >> 7, lm = tid & 127;
        const int bB = bwg * 2 + grp;
        float* s_h2 = s_aux;          // [2][256]
        float* s_wr2 = s_aux + 512;   // [2][128]
        float wwreg = (lm == 0) ? OMG_C : 0.f;
        float wureg = 0.f;

        for (int t = 0; t < TSTEPS; ++t) {
            if (wv == 0) wait_flags(g_fA + (size_t)t * NWG_A, NWG_A, t + 1, lane);
            else if (wv == 1 && t > 0) wait_flags(g_fC + (size_t)(t - 1) * NWG_C, NWG_C, t, lane);
            __syncthreads();
            asm volatile("" ::: "memory");
            s_h2[grp * 256 + lm] = g_hT[((size_t)t * HSZ + lm) * BATCH + bB];
            s_h2[grp * 256 + lm + 128] = g_hT[((size_t)t * HSZ + lm + 128) * BATCH + bB];
            __syncthreads();
            const float hv0 = s_h2[grp * 256 + lm], hv1 = s_h2[grp * 256 + lm + 128];
            const float hnorm = sqrtf(grpsum(hv0 * hv0 + hv1 * hv1));
            float sc = 0.f;
            if (t > 0) {
                const float4* mrow = (const float4*)&g_M[((size_t)t * MEMN + lm) * HSZ];
                const float4* h4 = (const float4*)&s_h2[grp * 256];
                float a = 0.f;
#pragma unroll 8
                for (int c = 0; c < 64; ++c) {
                    const float4 m4 = mrow[c], x4 = h4[c];
                    a += m4.x * x4.x + m4.y * x4.y + m4.z * x4.z + m4.w * x4.w;
                }
                const float mn = g_Mn[(size_t)t * MEMN + lm];
                sc = a / (hnorm * mn + 1e-8f);
            }
            const float mx = grpmax(sc);
            const float ev = expf(sc - mx);
            const float es = grpsum(ev);
            const float wr = ev / es;
            s_wr2[grp * 128 + lm] = wr;
            __syncthreads();
            float rd0 = 0.f, rd1 = 0.f;
            if (t > 0) {
#pragma unroll 8
                for (int m = 0; m < 128; ++m) {
                    const float mv = g_M[((size_t)t * MEMN + m) * HSZ + tid];
                    rd0 += s_wr2[m] * mv;
                    rd1 += s_wr2[128 + m] * mv;
                }
            }
            const int b0 = bwg * 2, b1 = b0 + 1;
            float* o0 = out + ((size_t)b0 * TSTEPS + t) * 512;
            float* o1 = out + ((size_t)b1 * TSTEPS + t) * 512;
            o0[tid] = s_h2[tid];
            o1[tid] = s_h2[256 + tid];
            o0[256 + tid] = rd0;
            o1[256 + tid] = rd1;
            // w_u(t+1) = l2norm(gamma*w_u + w_r + w_w(t)); w_w(t+1) from argmin
            const float un = GAMMA_C * wureg + wr + wwreg;
            const float un2 = grpsum(un * un);
            const float us = 1.0f / fmaxf(sqrtf(un2), 1e-12f);
            const float wun = un * us;
            wureg = wun;
            unsigned long long key =
                (((unsigned long long)__float_as_uint(wun)) << 32) | (unsigned)lm;
            const unsigned long long mk = grpminu(key);
            const int amin = (int)(mk & 0xffffffffu);
            const float wwn = GATE_C * wr + ((lm == amin) ? OMG_C : 0.f);
            wwreg = wwn;
            if (t + 1 < TSTEPS)
                st_wt(&g_ww[((size_t)(t + 1) * BATCH + bB) * MEMN + lm], wwn);
            wait_vm0();
            __syncthreads();
            if (tid == 0) st_flag(&g_fB[(size_t)t * NWG_B + bwg], t + 1);
        }
    } else {
        // ================= phase C: M(t+1) = l2norm(M(t) + ww(t)^T h(t)) =================
        const int cwg = w - NWG_A - NWG_B;
        const int m0 = cwg * 4;
        float* s_wwc = s_aux;  // [4][128]

        for (int t = 0; t < TSTEPS - 1; ++t) {
            if (wv == 0) wait_flags(g_fA + (size_t)t * NWG_A, NWG_A, t + 1, lane);
            else if (wv == 1 && t > 0) wait_flags(g_fB + (size_t)(t - 1) * NWG_B, NWG_B, t, lane);
            __syncthreads();
            asm volatile("" ::: "memory");
#pragma unroll
            for (int e = tid; e < 512; e += 256) {
                const int mi = e & 3, b = e >> 2;
                float v;
                if (t > 0) v = g_ww[((size_t)t * BATCH + b) * MEMN + m0 + mi];
                else v = (m0 + mi == 0) ? OMG_C : 0.f;
                s_wwc[mi * 128 + b] = v;
            }
            __syncthreads();
            float macc[4];
#pragma unroll
            for (int mi = 0; mi < 4; ++mi)
                macc[mi] = (t > 0) ? g_M[((size_t)t * MEMN + m0 + mi) * HSZ + tid] : 0.f;
            const float4* ht4 = (const float4*)&g_hT[((size_t)t * HSZ + tid) * BATCH];
#pragma unroll 4
            for (int b4 = 0; b4 < 32; ++b4) {
                const float4 hv4 = ht4[b4];
#pragma unroll
                for (int mi = 0; mi < 4; ++mi) {
                    const float* wc = &s_wwc[mi * 128 + b4 * 4];
                    macc[mi] += wc[0] * hv4.x + wc[1] * hv4.y + wc[2] * hv4.z + wc[3] * hv4.w;
                }
            }
#pragma unroll
            for (int mi = 0; mi < 4; ++mi) {
                const float nrm = sqrtf(red256sum(macc[mi] * macc[mi]));
                const float scale = 1.0f / fmaxf(nrm, 1e-12f);
                const float vo = macc[mi] * scale;
                st_wt(&g_M[((size_t)(t + 1) * MEMN + m0 + mi) * HSZ + tid], vo);
                if (tid == 0) st_wt(&g_Mn[(size_t)(t + 1) * MEMN + m0 + mi], nrm * scale);
            }
            wait_vm0();
            __syncthreads();
            if (tid == 0) st_flag(&g_fC[(size_t)t * NWG_C + cwg], t + 1);
        }
    }
}

extern "C" void kernel_launch(void* const* d_in, const int* in_sizes, int n_in,
                              void* d_out, int out_size, void* d_ws, size_t ws_size,
                              hipStream_t stream) {
    const float* X   = (const float*)d_in[0];
    const float* Wih = (const float*)d_in[1];
    const float* Whh = (const float*)d_in[2];
    const float* bih = (const float*)d_in[3];
    const float* bhh = (const float*)d_in[4];
    float* out = (float*)d_out;
    (void)in_sizes; (void)n_in; (void)out_size; (void)d_ws; (void)ws_size;

    hipLaunchKernelGGL(reset_ctrl_kernel, dim3(224), dim3(256), 0, stream);
    hipLaunchKernelGGL(mann_persist, dim3(NWG), dim3(NTHR), 0, stream,
                       X, Wih, Whh, bih, bhh, out);
}